// Round 13
// baseline (1834.659 us; speedup 1.0000x reference)
//
#include <hip/hip_runtime.h>

// 2-layer LSTM (B=256, T=512, D=64, H=256) + FC(256->4).
// Round-13: TWO-STREAM pipelining. 16 supergroups x 8 blocks; each block-set
// serves two independent batch groups A,B (16 batches) with shared
// register-resident weights. Superstep: MFMA(A); bar; act(A)+storeA, MFMA(B);
// bar; act(B)+storeB; stage(A); stage(B). Stream A's ring stores age
// ~MFMA(B)+act(B) before stage(A) reads them -> exchange latency hidden;
// only stream B's is exposed. Protocol unchanged from r12 (u64 packets
// {epoch32|2xf16}, relaxed agent atomics, ring-4, slack-2 cflag guard).
// Blocks 0-3: layer 0 quadrant q, 4-7: layer 1 quadrant q; systolic skew
// (iter s: L0 computes h0(s), L1 computes h1(s-1)) per stream, lockstep.

#define TT 512
#define HH 256
#define DD 64

typedef __attribute__((ext_vector_type(2))) _Float16 h2t;
typedef __attribute__((ext_vector_type(8))) _Float16 f16x8;
typedef __attribute__((ext_vector_type(4))) float f32x4;
typedef unsigned long long u64;
typedef unsigned u32;

__device__ __forceinline__ u32 pkh(float x, float y) {
    h2t h; h.x = (_Float16)x; h.y = (_Float16)y;
    return __builtin_bit_cast(u32, h);
}
__device__ __forceinline__ float sigf(float x) { return 1.f / (1.f + __expf(-x)); }
__device__ __forceinline__ float tanhf_(float x) {
    float e = __expf(2.f * x);
    return 1.f - 2.f / (e + 1.f);   // safe at +/-inf
}
__device__ __forceinline__ f16x8 ld8(const float* p) {
    float4 u = ((const float4*)p)[0];
    float4 v = ((const float4*)p)[1];
    f16x8 r = {(_Float16)u.x, (_Float16)u.y, (_Float16)u.z, (_Float16)u.w,
               (_Float16)v.x, (_Float16)v.y, (_Float16)v.z, (_Float16)v.w};
    return r;
}
__device__ __forceinline__ u32 ld32(const u32* p) {
    return __hip_atomic_load(p, __ATOMIC_RELAXED, __HIP_MEMORY_SCOPE_AGENT);
}
__device__ __forceinline__ void st32(u32* p, u32 v) {
    __hip_atomic_store(p, v, __ATOMIC_RELAXED, __HIP_MEMORY_SCOPE_AGENT);
}
__device__ __forceinline__ u64 ld64(const u64* p) {
    return __hip_atomic_load(p, __ATOMIC_RELAXED, __HIP_MEMORY_SCOPE_AGENT);
}
__device__ __forceinline__ void st64(u64* p, u64 v) {
    __hip_atomic_store(p, v, __ATOMIC_RELAXED, __HIP_MEMORY_SCOPE_AGENT);
}

__global__ __launch_bounds__(512, 2) void lstm_persist(
    const float* __restrict__ x,
    const float* __restrict__ Wih0, const float* __restrict__ Whh0,
    const float* __restrict__ bih0, const float* __restrict__ bhh0,
    const float* __restrict__ Wih1, const float* __restrict__ Whh1,
    const float* __restrict__ bih1, const float* __restrict__ bhh1,
    const float* __restrict__ fcW, const float* __restrict__ fcb,
    float* __restrict__ out,
    u64* h0ring, u64* h1ring, u32* cflagsA)
{
    __shared__ __align__(16) _Float16 sBA[9216];     // stream A: 64 ch x 144 halves
    __shared__ __align__(16) _Float16 sBB[9216];     // stream B
    __shared__ __align__(16) float p2A[2][8][276];   // k-split partials, A
    __shared__ __align__(16) float p2B[2][8][276];   // B

    const int tid  = threadIdx.x;
    const int sg   = blockIdx.x & 15;     // supergroup
    const int role = blockIdx.x >> 4;     // 0..7
    const bool isL1 = role >= 4;
    const int q = role & 3;
    const int gA = sg * 2, gB = sg * 2 + 1;
    const int batch0A = gA * 8, batch0B = gB * 8;
    u64* rA0 = h0ring + (size_t)gA * 4096;   // [slot4][q4][j8][hp32]
    u64* rA1 = h1ring + (size_t)gA * 4096;
    u64* rB0 = h0ring + (size_t)gB * 4096;
    u64* rB1 = h1ring + (size_t)gB * 4096;
    u32* cflag = cflagsA + (size_t)sg * 16;

    const int lane = tid & 63, w = tid >> 6;
    const int mw = w & 3, kh = w >> 2;
    const int bcol = lane & 15, kc = lane >> 4;

    // ---- A-fragment rows: wave mw owns gate mw; tiles ti=0..3 (r12 layout) ----
    const int R0 = mw * 256 + 64 * q + (lane & 15);
    const int R1 = R0 + 16, R2 = R0 + 32, R3 = R0 + 48;

#define DECL_TI(ti) f16x8 A##ti##_0={},A##ti##_1={},A##ti##_2={},A##ti##_3={}, \
                          A##ti##_4={},A##ti##_5={},A##ti##_6={},A##ti##_7={};
    DECL_TI(0) DECL_TI(1) DECL_TI(2) DECL_TI(3)
#undef DECL_TI

    if (isL1) {
#define LDA1(ti,j) { int k_ = (kh*8+(j))*32 + kc*8;                          \
        A##ti##_##j = ld8(k_ < 256 ? Wih1 + (size_t)R##ti*256 + k_           \
                                   : Whh1 + (size_t)R##ti*256 + (k_-256)); }
#define LDA1T(ti) LDA1(ti,0) LDA1(ti,1) LDA1(ti,2) LDA1(ti,3) \
                  LDA1(ti,4) LDA1(ti,5) LDA1(ti,6) LDA1(ti,7)
        LDA1T(0) LDA1T(1) LDA1T(2) LDA1T(3)
#undef LDA1T
#undef LDA1
    } else {
#define LDA0(ti,j) { int k_ = (kh*5+(j))*32 + kc*8;                          \
        A##ti##_##j = ld8(k_ < 64 ? Wih0 + (size_t)R##ti*64 + k_             \
                                  : Whh0 + (size_t)R##ti*256 + (k_-64)); }
#define LDA0T(ti) LDA0(ti,0) LDA0(ti,1) LDA0(ti,2) LDA0(ti,3) LDA0(ti,4)
        LDA0T(0) LDA0T(1) LDA0T(2) LDA0T(3)
#undef LDA0T
#undef LDA0
    }

    // ---- activation duty: thread (lane = h-idx in quadrant, w = batch) ----
    const float* bA = isL1 ? bih1 : bih0;
    const float* bB = isL1 ? bhh1 : bhh0;
    const float bz0 = bA[      64*q + lane] + bB[      64*q + lane];
    const float bz1 = bA[256 + 64*q + lane] + bB[256 + 64*q + lane];
    const float bz2 = bA[512 + 64*q + lane] + bB[512 + 64*q + lane];
    const float bz3 = bA[768 + 64*q + lane] + bB[768 + 64*q + lane];
    float cstA = 0.f, cstB = 0.f;

    u32* const sBuA = (u32*)sBA;
    u32* const sBuB = (u32*)sBB;
    for (int i = tid; i < 4608; i += 512) { sBuA[i] = 0; sBuB[i] = 0; }
    __syncthreads();   // zero-fill (pad rows + h(-1)=0) before x(0) staging

    // prologue: stage x(0) for both streams (L0 only; threads 256-511)
    if (!isL1 && tid >= 256) {
        const bool aA = tid < 384;
        int t2 = aA ? tid - 256 : tid - 384;
        int j = t2 >> 4, c = t2 & 15;
        float4 v = ((const float4*)(
            x + ((size_t)((aA ? batch0A : batch0B) + j) * TT) * DD))[c];
        u32* du = aA ? sBuA : sBuB;
        int bidx = (c >> 1) * 72 + j * 4 + 2 * (c & 1);
        du[bidx] = pkh(v.x, v.y); du[bidx + 1] = pkh(v.z, v.w);
    }

// MFMA over one stream's sB into its part2
#define MST(j, ktb, SBP) { const f16x8 Bf = *(const f16x8*)((SBP) + (((ktb)+(j))*4 + kc)*144 + bcol*8); \
    C0 = __builtin_amdgcn_mfma_f32_16x16x32_f16(A0_##j, Bf, C0, 0,0,0); \
    C1 = __builtin_amdgcn_mfma_f32_16x16x32_f16(A1_##j, Bf, C1, 0,0,0); \
    C2 = __builtin_amdgcn_mfma_f32_16x16x32_f16(A2_##j, Bf, C2, 0,0,0); \
    C3 = __builtin_amdgcn_mfma_f32_16x16x32_f16(A3_##j, Bf, C3, 0,0,0); }
#define MFMA_STREAM(SBP, P2) do {                                            \
    f32x4 C0={0,0,0,0},C1={0,0,0,0},C2={0,0,0,0},C3={0,0,0,0};               \
    if (isL1) { const int ktb = kh * 8;                                      \
        MST(0,ktb,SBP) MST(1,ktb,SBP) MST(2,ktb,SBP) MST(3,ktb,SBP)          \
        MST(4,ktb,SBP) MST(5,ktb,SBP) MST(6,ktb,SBP) MST(7,ktb,SBP)          \
    } else { const int ktb = kh * 5;                                         \
        MST(0,ktb,SBP) MST(1,ktb,SBP) MST(2,ktb,SBP) MST(3,ktb,SBP)          \
        MST(4,ktb,SBP) }                                                     \
    if (bcol < 8) {                                                          \
        *(f32x4*)&P2[kh][bcol][mw*64 +  0 + kc*4] = C0;                      \
        *(f32x4*)&P2[kh][bcol][mw*64 + 16 + kc*4] = C1;                      \
        *(f32x4*)&P2[kh][bcol][mw*64 + 32 + kc*4] = C2;                      \
        *(f32x4*)&P2[kh][bcol][mw*64 + 48 + kc*4] = C3;                      \
    } } while (0)

// activation + ring store for one stream (epoch s+1 packets)
#define ACT_STREAM(P2, CST, RBASE) do {                                      \
    float s0 = P2[0][w][      lane] + P2[1][w][      lane] + bz0;            \
    float s1 = P2[0][w][ 64 + lane] + P2[1][w][ 64 + lane] + bz1;            \
    float s2 = P2[0][w][128 + lane] + P2[1][w][128 + lane] + bz2;            \
    float s3 = P2[0][w][192 + lane] + P2[1][w][192 + lane] + bz3;            \
    float fi = sigf(s0), ff = sigf(s1), fg = tanhf_(s2), fo = sigf(s3);      \
    CST = ff * CST + fi * fg;                                                \
    float h = fo * tanhf_(CST);                                              \
    float hn = __shfl_down(h, 1);                                            \
    u32 hw = pkh(h, hn);                                                     \
    if (!(lane & 1)) {                                                       \
        u64 v = ((u64)(u32)(s + 1) << 32) | (u64)hw;                         \
        st64((RBASE) + q * 256 + w * 32 + (lane >> 1), v);                   \
    } } while (0)

    for (int s = 0; s <= TT; ++s) {
        __syncthreads();   // staging(s) complete for both streams
        if (tid == 0) st32(&cflag[role], (u32)(s + 1));

        const bool act_ = isL1 ? (s >= 1) : (s < TT);
        const int  snx  = s + 1;
        const bool stg0 = (!isL1) && (snx < TT);
        const bool stg1 = isL1 && (snx <= TT);

        // guard-flag preload + x prefetch (both protocol-free, hide under MFMA)
        u32 cpre = 0u;
        if (act_ && lane < 8) cpre = ld32(&cflag[lane]);
        float4 xr;
        const bool doXA = stg0 && tid >= 256 && tid < 384;
        const bool doXB = stg0 && tid >= 384;
        if (doXA || doXB) {
            int t2 = doXA ? tid - 256 : tid - 384;
            int j = t2 >> 4, c = t2 & 15;
            int b0x = doXA ? batch0A : batch0B;
            xr = ((const float4*)(x + ((size_t)(b0x + j) * TT + snx) * DD))[c];
        }

        if (act_) MFMA_STREAM(sBA, p2A);
        __syncthreads();   // p2A ready; sBA reads done

        if (act_) {
            // ring-overwrite guard (covers both streams; flags monotone)
            const int tgt = s - 2;
            while (!__all(lane >= 8 || (int)cpre >= tgt)) {
                __builtin_amdgcn_s_sleep(1);
                if (lane < 8) cpre = ld32(&cflag[lane]);
            }
            ACT_STREAM(p2A, cstA,
                       (isL1 ? rA1 + (size_t)((s - 1) & 3) * 1024
                             : rA0 + (size_t)(s & 3) * 1024));
            MFMA_STREAM(sBB, p2B);
        }
        __syncthreads();   // p2B ready; sBB reads done; act(A) done

        if (act_) {
            ACT_STREAM(p2B, cstB,
                       (isL1 ? rB1 + (size_t)((s - 1) & 3) * 1024
                             : rB0 + (size_t)(s & 3) * 1024));
        }

        // ---- stage s+1 for BOTH streams: joint issue, one retry loop ----
        // Stream A's producers stored ~MFMA(B)+act(B) ago -> likely visible.
        if (stg0 || stg1) {
            const int n0  = tid & 127;
            const int jj0 = tid >> 7, jj1 = 4 + jj0;
            const size_t qoff = (size_t)((n0 >> 5) << 8) + (n0 & 31);
            const u64* bA0 = rA0 + (size_t)((snx - 1) & 3) * 1024 + qoff;
            const u64* bB0 = rB0 + (size_t)((snx - 1) & 3) * 1024 + qoff;
            const u64 *aA00 = bA0 + jj0*32, *aA01 = bA0 + jj1*32;
            const u64 *aB00 = bB0 + jj0*32, *aB01 = bB0 + jj1*32;
            u64 vA00 = ld64(aA00), vA01 = ld64(aA01);
            u64 vB00 = ld64(aB00), vB01 = ld64(aB01);
            u64 vA10 = 0, vA11 = 0, vB10 = 0, vB11 = 0;
            const u64 *aA10 = nullptr, *aA11 = nullptr,
                      *aB10 = nullptr, *aB11 = nullptr;
            if (isL1) {
                const u64* bA1 = rA1 + (size_t)((snx + 2) & 3) * 1024 + qoff;
                const u64* bB1 = rB1 + (size_t)((snx + 2) & 3) * 1024 + qoff;
                aA10 = bA1 + jj0*32; aA11 = bA1 + jj1*32;
                aB10 = bB1 + jj0*32; aB11 = bB1 + jj1*32;
                vA10 = ld64(aA10); vA11 = ld64(aA11);
                vB10 = ld64(aB10); vB11 = ld64(aB11);
            }
            const u32 e0 = (u32)snx;
            const u32 e1 = (snx >= 2) ? (u32)snx : 0u;
            for (;;) {
                bool kA0 = ((u32)(vA00 >> 32) == e0);
                bool kA1 = ((u32)(vA01 >> 32) == e0);
                bool kB0 = ((u32)(vB00 >> 32) == e0);
                bool kB1 = ((u32)(vB01 >> 32) == e0);
                bool kA2 = !isL1 || ((u32)(vA10 >> 32) == e1);
                bool kA3 = !isL1 || ((u32)(vA11 >> 32) == e1);
                bool kB2 = !isL1 || ((u32)(vB10 >> 32) == e1);
                bool kB3 = !isL1 || ((u32)(vB11 >> 32) == e1);
                if (kA0 & kA1 & kB0 & kB1 & kA2 & kA3 & kB2 & kB3) break;
                if (!kA0) vA00 = ld64(aA00);
                if (!kA1) vA01 = ld64(aA01);
                if (!kB0) vB00 = ld64(aB00);
                if (!kB1) vB01 = ld64(aB01);
                if (isL1) {
                    if (!kA2) vA10 = ld64(aA10);
                    if (!kA3) vA11 = ld64(aA11);
                    if (!kB2) vB10 = ld64(aB10);
                    if (!kB3) vB11 = ld64(aB11);
                }
            }
            const int cb0 = isL1 ? 0 : 8;
            const int oj0 = (cb0 + (n0 >> 2)) * 72 + jj0 * 4 + (n0 & 3);
            const int oj1 = (cb0 + (n0 >> 2)) * 72 + jj1 * 4 + (n0 & 3);
            sBuA[oj0] = (u32)vA00; sBuA[oj1] = (u32)vA01;
            sBuB[oj0] = (u32)vB00; sBuB[oj1] = (u32)vB01;
            if (isL1) {
                const int pj0 = (32 + (n0 >> 2)) * 72 + jj0 * 4 + (n0 & 3);
                const int pj1 = (32 + (n0 >> 2)) * 72 + jj1 * 4 + (n0 & 3);
                sBuA[pj0] = (u32)vA10; sBuA[pj1] = (u32)vA11;
                sBuB[pj0] = (u32)vB10; sBuB[pj1] = (u32)vB11;
            }
            if (doXA || doXB) {
                int t2 = doXA ? tid - 256 : tid - 384;
                int j = t2 >> 4, c = t2 & 15;
                u32* du = doXA ? sBuA : sBuB;
                int bidx = (c >> 1) * 72 + j * 4 + 2 * (c & 1);
                du[bidx]     = pkh(xr.x, xr.y);
                du[bidx + 1] = pkh(xr.z, xr.w);
            }
        }
    }
#undef MST
#undef MFMA_STREAM
#undef ACT_STREAM

    // ---- final FC on h1(TT-1) for both streams: ring slot 3, epoch TT+1 ----
    if (isL1 && q == 0) {
        const u32 ef = (u32)(TT + 1);
        const int n0  = tid & 127;
        const int jj0 = tid >> 7, jj1 = 4 + jj0;
        const size_t qoff = (size_t)((n0 >> 5) << 8) + (n0 & 31);
        const u64* bA = rA1 + 3 * 1024 + qoff;
        const u64* bB = rB1 + 3 * 1024 + qoff;
        const u64 *a0 = bA + jj0*32, *a1 = bA + jj1*32;
        const u64 *a2 = bB + jj0*32, *a3 = bB + jj1*32;
        u64 v0 = ld64(a0), v1 = ld64(a1), v2 = ld64(a2), v3 = ld64(a3);
        for (;;) {
            bool k0 = ((u32)(v0 >> 32) == ef), k1 = ((u32)(v1 >> 32) == ef);
            bool k2 = ((u32)(v2 >> 32) == ef), k3 = ((u32)(v3 >> 32) == ef);
            if (k0 & k1 & k2 & k3) break;
            if (!k0) v0 = ld64(a0);  if (!k1) v1 = ld64(a1);
            if (!k2) v2 = ld64(a2);  if (!k3) v3 = ld64(a3);
        }
        sBuA[jj0 * 128 + n0] = (u32)v0;   // flat [batch][128 u32] per stream
        sBuA[jj1 * 128 + n0] = (u32)v1;
        sBuB[jj0 * 128 + n0] = (u32)v2;
        sBuB[jj1 * 128 + n0] = (u32)v3;
        __syncthreads();
        const int j = tid >> 5;              // 0..15 (A: 0-7, B: 8-15)
        const int l2 = tid & 31, o = l2 >> 3, kk = l2 & 7;
        const _Float16* hsrc = (j < 8) ? (sBA + j * 256) : (sBB + (j - 8) * 256);
        float ssum = 0.f;
#pragma unroll
        for (int m = 0; m < 32; ++m) {
            int k = kk * 32 + m;
            ssum += (float)hsrc[k] * fcW[o * HH + k];
        }
        ssum += __shfl_down(ssum, 4);
        ssum += __shfl_down(ssum, 2);
        ssum += __shfl_down(ssum, 1);
        if (kk == 0) out[(sg * 16 + j) * 4 + o] = ssum + fcb[o];
    }
}

extern "C" void kernel_launch(void* const* d_in, const int* in_sizes, int n_in,
                              void* d_out, int out_size, void* d_ws, size_t ws_size,
                              hipStream_t stream)
{
    (void)in_sizes; (void)n_in; (void)out_size; (void)ws_size;
    const float* x    = (const float*)d_in[0];
    const float* Wih0 = (const float*)d_in[1];
    const float* Whh0 = (const float*)d_in[2];
    const float* bih0 = (const float*)d_in[3];
    const float* bhh0 = (const float*)d_in[4];
    const float* Wih1 = (const float*)d_in[5];
    const float* Whh1 = (const float*)d_in[6];
    const float* bih1 = (const float*)d_in[7];
    const float* bhh1 = (const float*)d_in[8];
    const float* fcW  = (const float*)d_in[9];
    const float* fcb  = (const float*)d_in[10];
    float* out = (float*)d_out;

    // ws: h0ring 1MB (32 grp x 4 slot x 1024 u64) | h1ring 1MB | cflags 2KB
    u64* h0ring = (u64*)d_ws;
    u64* h1ring = (u64*)((char*)d_ws + 1048576);
    u32* cflags = (u32*)((char*)d_ws + 2097152);

    hipMemsetAsync(d_ws, 0, 2097152 + 2048, stream);   // epoch 0 == h(-1)=0

    lstm_persist<<<dim3(128), dim3(512), 0, stream>>>(
        x, Wih0, Whh0, bih0, bhh0, Wih1, Whh1, bih1, bhh1, fcW, fcb, out,
        h0ring, h1ring, cflags);
}